// Round 6
// baseline (1338.751 us; speedup 1.0000x reference)
//
#include <hip/hip_runtime.h>

#define DV 1024
#define TT 4096
#define BB 4
#define FF 4096
#define MM (BB*TT)   // 16384 rows
#define NCH 64       // WKV chunks
#define LCH 64       // WKV chunk length (NCH*LCH == TT)

typedef __attribute__((ext_vector_type(8))) short bf16x8;
typedef __attribute__((ext_vector_type(4))) float f32x4;
typedef __attribute__((ext_vector_type(8))) unsigned short u16x8;
typedef __attribute__((ext_vector_type(4))) unsigned short u16x4;

__device__ __forceinline__ float bf2f(unsigned short h) {
    union { unsigned int u; float f; } c; c.u = ((unsigned int)h) << 16; return c.f;
}
__device__ __forceinline__ unsigned short f2bf(float f) {
    union { float f; unsigned int u; } c; c.f = f;
    unsigned int r = c.u + 0x7fffu + ((c.u >> 16) & 1u);
    return (unsigned short)(r >> 16);
}

// async global->LDS, 16B per lane; LDS dest must be wave-uniform base (HW adds lane*16)
__device__ __forceinline__ void gl16(const void* g, void* l) {
    __builtin_amdgcn_global_load_lds(
        (const __attribute__((address_space(1))) void*)g,
        (__attribute__((address_space(3))) void*)l, 16, 0, 0);
}

// diag: if workspace too small, expose ws_size via absmax
__global__ void diag_kernel(float* out, float v) { out[0] = v; }

// ---------------- weight cast+transpose: f32 [K][N] -> bf16 [N][K] ----------------
__global__ __launch_bounds__(256) void transpose_cast(
    const float* __restrict__ src, unsigned short* __restrict__ dst, int K, int N)
{
    __shared__ float t[32][33];
    int n0 = blockIdx.x * 32, k0 = blockIdx.y * 32;
    int tx = threadIdx.x, ty = threadIdx.y;  // block (32,8)
    #pragma unroll
    for (int i = 0; i < 4; ++i)
        t[ty*4+i][tx] = src[(size_t)(k0 + ty*4 + i) * N + n0 + tx];
    __syncthreads();
    #pragma unroll
    for (int i = 0; i < 4; ++i)
        dst[(size_t)(n0 + ty*4 + i) * K + k0 + tx] = f2bf(t[tx][ty*4+i]);
}

// ---------------- LayerNorm: (f32|bf16) [rows][1024] -> bf16 ----------------
template<bool BF16IN>
__global__ __launch_bounds__(256) void ln_kernel(
    const void* __restrict__ xin, const float* __restrict__ w, const float* __restrict__ b,
    unsigned short* __restrict__ out)
{
    int row = blockIdx.x;
    int t = threadIdx.x;
    float v0, v1, v2, v3;
    if (BF16IN) {
        u16x4 h = *(const u16x4*)((const unsigned short*)xin + (size_t)row * DV + t * 4);
        v0 = bf2f(h[0]); v1 = bf2f(h[1]); v2 = bf2f(h[2]); v3 = bf2f(h[3]);
    } else {
        float4 v = ((const float4*)((const float*)xin + (size_t)row * DV))[t];
        v0 = v.x; v1 = v.y; v2 = v.z; v3 = v.w;
    }
    float s = v0 + v1 + v2 + v3;
    float q = v0*v0 + v1*v1 + v2*v2 + v3*v3;
    #pragma unroll
    for (int off = 32; off >= 1; off >>= 1) {
        s += __shfl_down(s, off);
        q += __shfl_down(q, off);
    }
    __shared__ float ss[4], qq[4];
    if ((t & 63) == 0) { ss[t >> 6] = s; qq[t >> 6] = q; }
    __syncthreads();
    s = ss[0] + ss[1] + ss[2] + ss[3];
    q = qq[0] + qq[1] + qq[2] + qq[3];
    float mu = s * (1.f/DV);
    float var = q * (1.f/DV) - mu*mu;
    float rs = rsqrtf(var + 1e-5f);
    int d = t * 4;
    u16x4 o;
    o[0] = f2bf((v0 - mu)*rs*w[d+0] + b[d+0]);
    o[1] = f2bf((v1 - mu)*rs*w[d+1] + b[d+1]);
    o[2] = f2bf((v2 - mu)*rs*w[d+2] + b[d+2]);
    o[3] = f2bf((v3 - mu)*rs*w[d+3] + b[d+3]);
    *(u16x4*)(out + (size_t)row*DV + d) = o;
}

// ---------------- time-shift mix: out = xn*c + shift(xn)*(1-c), 2 or 3 outputs ----------------
__global__ __launch_bounds__(256) void mix_kernel(
    const unsigned short* __restrict__ xn,
    const float* __restrict__ ck, const float* __restrict__ cv, const float* __restrict__ cr,
    unsigned short* __restrict__ ok, unsigned short* __restrict__ ov, unsigned short* __restrict__ orr)
{
    int gid = blockIdx.x * 256 + threadIdx.x;   // MM*DV/8 total
    int row = gid >> 7;
    int d0 = (gid & 127) << 3;
    size_t base = (size_t)row * DV + d0;
    u16x8 cur = *(const u16x8*)(xn + base);
    bool hp = (row & (TT - 1)) != 0;
    u16x8 prev = (u16x8)0;
    if (hp) prev = *(const u16x8*)(xn + base - DV);
    u16x8 rk, rv, rr2;
    #pragma unroll
    for (int e = 0; e < 8; ++e) {
        float xc = bf2f(cur[e]);
        float xp = hp ? bf2f(prev[e]) : 0.f;
        float a = ck[d0+e]; rk[e] = f2bf(xc*a + xp*(1.f-a));
        float bb = cv[d0+e]; rv[e] = f2bf(xc*bb + xp*(1.f-bb));
        if (orr) { float c = cr[d0+e]; rr2[e] = f2bf(xc*c + xp*(1.f-c)); }
    }
    *(u16x8*)(ok + base) = rk;
    *(u16x8*)(ov + base) = rv;
    if (orr) *(u16x8*)(orr + base) = rr2;
}

// ---------------- WKV chunk-parallel scan ----------------
__global__ __launch_bounds__(256) void wkv_phase1(
    const unsigned short* __restrict__ k, const unsigned short* __restrict__ v,
    const float* __restrict__ time_decay,
    float* __restrict__ saP, float* __restrict__ sbP, float* __restrict__ mP)
{
    int gid = blockIdx.x * 256 + threadIdx.x;      // 262144
    int d = gid & (DV - 1);
    int bc = gid >> 10;
    int b = bc >> 6, c = bc & (NCH - 1);
    float w = __expf(time_decay[d]);
    float alpha = 0.f, beta = 0.f, m = -1e30f;
    size_t base = ((size_t)b * TT + (size_t)c * LCH) * DV + d;
    for (int t = 0; t < LCH; ++t) {
        size_t idx = base + (size_t)t * DV;
        float kt = bf2f(k[idx]);
        float vt = bf2f(v[idx]);
        float wm = m - w;
        float tau = fmaxf(wm, kt);
        float d1 = __expf(wm - tau);
        float d2 = __expf(kt - tau);
        alpha = d1*alpha + d2*vt;
        beta  = d1*beta + d2;
        m = tau;
    }
    saP[gid] = alpha; sbP[gid] = beta; mP[gid] = m;
}

__global__ __launch_bounds__(256) void wkv_phase2(
    const float* __restrict__ time_decay,
    float* __restrict__ saP, float* __restrict__ sbP, float* __restrict__ mP)
{
    int gid = blockIdx.x * 256 + threadIdx.x;      // 4096
    int b = gid >> 10, d = gid & (DV - 1);
    float Lw = (float)LCH * __expf(time_decay[d]);
    float A = 0.f, Bv = 0.f, E = -1e30f;
    for (int c = 0; c < NCH; ++c) {
        int idx = ((b * NCH + c) << 10) + d;
        float sa = saP[idx], sb = sbP[idx], mc = mP[idx];
        saP[idx] = A; sbP[idx] = Bv; mP[idx] = E;
        float de = E - Lw;
        float m2 = fmaxf(de, mc);
        float e1 = __expf(de - m2);
        float e2 = __expf(mc - m2);
        A  = e1*A  + e2*sa;
        Bv = e1*Bv + e2*sb;
        E  = m2;
    }
}

__global__ __launch_bounds__(256) void wkv_phase3(
    const unsigned short* __restrict__ k, const unsigned short* __restrict__ v,
    const unsigned short* __restrict__ r,
    const float* __restrict__ time_decay, const float* __restrict__ time_first,
    const float* __restrict__ saP, const float* __restrict__ sbP, const float* __restrict__ mP,
    unsigned short* __restrict__ aout)
{
    int gid = blockIdx.x * 256 + threadIdx.x;      // 262144
    int d = gid & (DV - 1);
    int bc = gid >> 10;
    int b = bc >> 6, c = bc & (NCH - 1);
    float w = __expf(time_decay[d]);
    float u = time_first[d];
    float alpha = saP[gid], beta = sbP[gid], eps = mP[gid];
    size_t base = ((size_t)b * TT + (size_t)c * LCH) * DV + d;
    for (int t = 0; t < LCH; ++t) {
        size_t idx = base + (size_t)t * DV;
        float kt = bf2f(k[idx]);
        float vt = bf2f(v[idx]);
        float ukt = u + kt;
        float tau = fmaxf(ukt, eps);
        float e1 = __expf(eps - tau);
        float e2 = __expf(ukt - tau);
        float out = (e1*alpha + e2*vt) / (e1*beta + e2);
        float weps = eps - w;
        float tau2 = fmaxf(weps, kt);
        float d1 = __expf(weps - tau2);
        float d2 = __expf(kt - tau2);
        alpha = d1*alpha + d2*vt;
        beta  = d1*beta + d2;
        eps = tau2;
        float rt = bf2f(r[idx]);
        float sr = 1.f / (1.f + __expf(-rt));
        aout[idx] = f2bf(out * sr);
    }
}

// ---------------- bf16 MFMA GEMM (m97 structure): C = A[M,K] @ Bt[N,K]^T ----------------
// global_load_lds(16B) staging, linear [128][32] LDS tiles, 2-barrier K-loop.
// MODE 1: C bf16 = acc
// MODE 3: C bf16 = relu(acc)^2
// MODE 5: C bf16 = acc + res_f32
// MODE 7: C f32  = acc
// MODE 8: C f32 += acc
// MODE 9: C f32  = res_bf16 + sigmoid(gate_bf16) * (Cprev + acc)
template<int MODE>
__global__ __launch_bounds__(256) void gemm_bf16(
    const short* __restrict__ A, const short* __restrict__ Bt,
    void* __restrict__ Cout, int M, int N, int K,
    const void* __restrict__ res, const unsigned short* __restrict__ gate)
{
    __shared__ short sA[128 * 32];
    __shared__ short sB[128 * 32];
    const int m0 = blockIdx.y * 128, n0 = blockIdx.x * 128;
    const int t = threadIdx.x;
    const int lane = t & 63, wv = t >> 6;
    const int wr = wv >> 1, wc = wv & 1;
    const int lm = lane & 15, lk = (lane >> 4) * 8;
    // staging geometry: chunk = 1024 B = 16 rows of 32 shorts; 8 chunks per tile;
    // wave wv stages chunks {wv, wv+4} of both A and B; lane covers 16B at
    // row (chunk*16 + lane/4), shorts (lane&3)*8.
    const int srow = lane >> 2;
    const int scol = (lane & 3) * 8;
    f32x4 acc[4][4] = {};

    for (int k0 = 0; k0 < K; k0 += 32) {
        __syncthreads();   // previous iteration's ds_reads complete
        #pragma unroll
        for (int i = 0; i < 2; ++i) {
            int c = wv + i * 4;
            int row = c * 16 + srow;
            gl16(A  + (size_t)(m0 + row) * K + k0 + scol, sA + c * 512);
            gl16(Bt + (size_t)(n0 + row) * K + k0 + scol, sB + c * 512);
        }
        __syncthreads();   // compiler drains vmcnt(0) before barrier
        bf16x8 af[4], bfr[4];
        #pragma unroll
        for (int i = 0; i < 4; ++i)
            af[i] = *(const bf16x8*)&sA[(wr*64 + i*16 + lm) * 32 + lk];
        #pragma unroll
        for (int j = 0; j < 4; ++j)
            bfr[j] = *(const bf16x8*)&sB[(wc*64 + j*16 + lm) * 32 + lk];
        #pragma unroll
        for (int i = 0; i < 4; ++i)
            #pragma unroll
            for (int j = 0; j < 4; ++j)
                acc[i][j] = __builtin_amdgcn_mfma_f32_16x16x32_bf16(af[i], bfr[j], acc[i][j], 0, 0, 0);
    }

    #pragma unroll
    for (int i = 0; i < 4; ++i)
        #pragma unroll
        for (int j = 0; j < 4; ++j)
            #pragma unroll
            for (int rr = 0; rr < 4; ++rr) {
                int gm = m0 + wr*64 + i*16 + (lane >> 4)*4 + rr;
                int gn = n0 + wc*64 + j*16 + lm;
                size_t off = (size_t)gm * N + gn;
                float val = acc[i][j][rr];
                if (MODE == 1) {
                    ((unsigned short*)Cout)[off] = f2bf(val);
                } else if (MODE == 3) {
                    float rl = fmaxf(val, 0.f);
                    ((unsigned short*)Cout)[off] = f2bf(rl * rl);
                } else if (MODE == 5) {
                    ((unsigned short*)Cout)[off] = f2bf(val + ((const float*)res)[off]);
                } else if (MODE == 7) {
                    ((float*)Cout)[off] = val;
                } else if (MODE == 8) {
                    ((float*)Cout)[off] += val;
                } else {
                    float g = bf2f(gate[off]);
                    float sg = 1.f / (1.f + __expf(-g));
                    float sum = ((float*)Cout)[off] + val;
                    ((float*)Cout)[off] = bf2f(((const unsigned short*)res)[off]) + sg * sum;
                }
            }
}

extern "C" void kernel_launch(void* const* d_in, const int* in_sizes, int n_in,
                              void* d_out, int out_size, void* d_ws, size_t ws_size,
                              hipStream_t stream) {
    const float* x          = (const float*)d_in[0];
    const float* ln1_w      = (const float*)d_in[1];
    const float* ln1_b      = (const float*)d_in[2];
    const float* ln2_w      = (const float*)d_in[3];
    const float* ln2_b      = (const float*)d_in[4];
    const float* time_decay = (const float*)d_in[5];
    const float* time_first = (const float*)d_in[6];
    const float* tmk        = (const float*)d_in[7];
    const float* tmv        = (const float*)d_in[8];
    const float* tmr        = (const float*)d_in[9];
    const float* w_key      = (const float*)d_in[10];
    const float* w_value    = (const float*)d_in[11];
    const float* w_recept   = (const float*)d_in[12];
    const float* w_output   = (const float*)d_in[13];
    const float* f_tmk      = (const float*)d_in[14];
    const float* f_tmr      = (const float*)d_in[15];
    const float* f_w_key    = (const float*)d_in[16];
    const float* f_w_recept = (const float*)d_in[17];
    const float* f_w_value  = (const float*)d_in[18];

    char* ws = (char*)d_ws;
    const size_t MB = 1ull << 20;
    if (ws_size < 160 * MB) {
        diag_kernel<<<1, 1, 0, stream>>>((float*)d_out, (float)ws_size);
        return;
    }

    // weights (bf16, transposed [N][K]) — 26 MiB total
    unsigned short* wkT  = (unsigned short*)(ws + 0*MB);    // [1024][1024]
    unsigned short* wvT  = (unsigned short*)(ws + 2*MB);
    unsigned short* wrT  = (unsigned short*)(ws + 4*MB);
    unsigned short* woT  = (unsigned short*)(ws + 6*MB);
    unsigned short* fwkT = (unsigned short*)(ws + 8*MB);    // [4096][1024]
    unsigned short* fwrT = (unsigned short*)(ws + 16*MB);   // [1024][1024]
    unsigned short* fwvT = (unsigned short*)(ws + 18*MB);   // 4 x [1024][1024] (per F-chunk)
    // WKV chunk summaries: 3 planes x 1 MiB
    float* saP = (float*)(ws + 26*MB);
    float* sbP = (float*)(ws + 27*MB);
    float* mP  = (float*)(ws + 28*MB);
    // four rotating 32-MiB activation slots ([16384][1024] bf16 each)
    unsigned short* S0 = (unsigned short*)(ws + 32*MB);
    unsigned short* S1 = (unsigned short*)(ws + 64*MB);
    unsigned short* S2 = (unsigned short*)(ws + 96*MB);
    unsigned short* S3 = (unsigned short*)(ws + 128*MB);
    // liveness-checked aliases
    unsigned short* xn    = S0;
    unsigned short* xk    = S1;
    unsigned short* xv    = S2;
    unsigned short* xr    = S3;
    unsigned short* kbuf  = S0;  // xn dead
    unsigned short* vbuf  = S1;  // xk dead
    unsigned short* rbuf  = S2;  // xv dead
    unsigned short* abuf  = S3;  // xr dead
    unsigned short* x1    = S0;  // kbuf dead (bf16 residual)
    unsigned short* xn2   = S1;  // vbuf dead
    unsigned short* fkx   = S2;  // rbuf dead
    unsigned short* frx   = S3;  // abuf dead
    unsigned short* frbuf = S1;  // xn2 dead
    unsigned short* hkf   = S3;  // frx dead ([16384][1024] bf16 per F-chunk)

    dim3 tb(32, 8);
    transpose_cast<<<dim3(32, 32),  tb, 0, stream>>>(w_key,      wkT,  1024, 1024);
    transpose_cast<<<dim3(32, 32),  tb, 0, stream>>>(w_value,    wvT,  1024, 1024);
    transpose_cast<<<dim3(32, 32),  tb, 0, stream>>>(w_recept,   wrT,  1024, 1024);
    transpose_cast<<<dim3(32, 32),  tb, 0, stream>>>(w_output,   woT,  1024, 1024);
    transpose_cast<<<dim3(128, 32), tb, 0, stream>>>(f_w_key,    fwkT, 1024, 4096);
    transpose_cast<<<dim3(32, 32),  tb, 0, stream>>>(f_w_recept, fwrT, 1024, 1024);
    for (int f = 0; f < 4; ++f)   // f_w_value K-chunk f -> [1024][1024] at fwvT + f*1M
        transpose_cast<<<dim3(32, 32), tb, 0, stream>>>(
            f_w_value + (size_t)f * 1024 * 1024, fwvT + (size_t)f * 1024 * 1024, 1024, 1024);

    // --- attention sub-block ---
    ln_kernel<false><<<MM, 256, 0, stream>>>(x, ln1_w, ln1_b, xn);
    mix_kernel<<<MM*DV/8/256, 256, 0, stream>>>(xn, tmk, tmv, tmr, xk, xv, xr);
    gemm_bf16<1><<<dim3(8, 128), 256, 0, stream>>>((const short*)xk, (const short*)wkT, kbuf, MM, 1024, 1024, nullptr, nullptr);
    gemm_bf16<1><<<dim3(8, 128), 256, 0, stream>>>((const short*)xv, (const short*)wvT, vbuf, MM, 1024, 1024, nullptr, nullptr);
    gemm_bf16<1><<<dim3(8, 128), 256, 0, stream>>>((const short*)xr, (const short*)wrT, rbuf, MM, 1024, 1024, nullptr, nullptr);
    wkv_phase1<<<BB*NCH*DV/256, 256, 0, stream>>>(kbuf, vbuf, time_decay, saP, sbP, mP);
    wkv_phase2<<<BB*DV/256, 256, 0, stream>>>(time_decay, saP, sbP, mP);
    wkv_phase3<<<BB*NCH*DV/256, 256, 0, stream>>>(kbuf, vbuf, rbuf, time_decay, time_first, saP, sbP, mP, abuf);
    gemm_bf16<5><<<dim3(8, 128), 256, 0, stream>>>((const short*)abuf, (const short*)woT, x1, MM, 1024, 1024, x, nullptr);

    // --- feed-forward sub-block (F-chunked: all GEMMs M=16384,N=1024,K=1024) ---
    ln_kernel<true><<<MM, 256, 0, stream>>>(x1, ln2_w, ln2_b, xn2);
    mix_kernel<<<MM*DV/8/256, 256, 0, stream>>>(xn2, f_tmk, f_tmr, nullptr, fkx, frx, nullptr);
    gemm_bf16<1><<<dim3(8, 128), 256, 0, stream>>>((const short*)frx, (const short*)fwrT, frbuf, MM, 1024, 1024, nullptr, nullptr);
    for (int f = 0; f < 4; ++f) {
        const short* fwk_f = (const short*)(fwkT + (size_t)f * 1024 * 1024);  // rows f*1024..
        const short* fwv_f = (const short*)(fwvT + (size_t)f * 1024 * 1024);
        gemm_bf16<3><<<dim3(8, 128), 256, 0, stream>>>((const short*)fkx, fwk_f, hkf, MM, 1024, 1024, nullptr, nullptr);
        if (f == 0)
            gemm_bf16<7><<<dim3(8, 128), 256, 0, stream>>>((const short*)hkf, fwv_f, (float*)d_out, MM, 1024, 1024, nullptr, nullptr);
        else if (f < 3)
            gemm_bf16<8><<<dim3(8, 128), 256, 0, stream>>>((const short*)hkf, fwv_f, (float*)d_out, MM, 1024, 1024, nullptr, nullptr);
        else
            gemm_bf16<9><<<dim3(8, 128), 256, 0, stream>>>((const short*)hkf, fwv_f, (float*)d_out, MM, 1024, 1024, x1, frbuf);
    }
}

// Round 7
// 1091.458 us; speedup vs baseline: 1.2266x; 1.2266x over previous
//
#include <hip/hip_runtime.h>

#define DV 1024
#define TT 4096
#define BB 4
#define FF 4096
#define MM (BB*TT)   // 16384 rows
#define NCH 64       // WKV chunks
#define LCH 64       // WKV chunk length (NCH*LCH == TT)

typedef __attribute__((ext_vector_type(8))) short bf16x8;
typedef __attribute__((ext_vector_type(4))) float f32x4;
typedef __attribute__((ext_vector_type(8))) unsigned short u16x8;
typedef __attribute__((ext_vector_type(4))) unsigned short u16x4;

__device__ __forceinline__ float bf2f(unsigned short h) {
    union { unsigned int u; float f; } c; c.u = ((unsigned int)h) << 16; return c.f;
}
__device__ __forceinline__ unsigned short f2bf(float f) {
    union { float f; unsigned int u; } c; c.f = f;
    unsigned int r = c.u + 0x7fffu + ((c.u >> 16) & 1u);
    return (unsigned short)(r >> 16);
}

// async global->LDS, 16B per lane; LDS dest must be wave-uniform base (HW adds lane*16)
__device__ __forceinline__ void gl16(const void* g, void* l) {
    __builtin_amdgcn_global_load_lds(
        (const __attribute__((address_space(1))) void*)g,
        (__attribute__((address_space(3))) void*)l, 16, 0, 0);
}

// diag: if workspace too small, expose ws_size via absmax
__global__ void diag_kernel(float* out, float v) { out[0] = v; }

// ---------------- weight cast+transpose: f32 [K][N] -> bf16 [N][K] ----------------
__global__ __launch_bounds__(256) void transpose_cast(
    const float* __restrict__ src, unsigned short* __restrict__ dst, int K, int N)
{
    __shared__ float t[32][33];
    int n0 = blockIdx.x * 32, k0 = blockIdx.y * 32;
    int tx = threadIdx.x, ty = threadIdx.y;  // block (32,8)
    #pragma unroll
    for (int i = 0; i < 4; ++i)
        t[ty*4+i][tx] = src[(size_t)(k0 + ty*4 + i) * N + n0 + tx];
    __syncthreads();
    #pragma unroll
    for (int i = 0; i < 4; ++i)
        dst[(size_t)(n0 + ty*4 + i) * K + k0 + tx] = f2bf(t[tx][ty*4+i]);
}

// ---------------- LayerNorm: (f32|bf16) [rows][1024] -> bf16 ----------------
template<bool BF16IN>
__global__ __launch_bounds__(256) void ln_kernel(
    const void* __restrict__ xin, const float* __restrict__ w, const float* __restrict__ b,
    unsigned short* __restrict__ out)
{
    int row = blockIdx.x;
    int t = threadIdx.x;
    float v0, v1, v2, v3;
    if (BF16IN) {
        u16x4 h = *(const u16x4*)((const unsigned short*)xin + (size_t)row * DV + t * 4);
        v0 = bf2f(h[0]); v1 = bf2f(h[1]); v2 = bf2f(h[2]); v3 = bf2f(h[3]);
    } else {
        float4 v = ((const float4*)((const float*)xin + (size_t)row * DV))[t];
        v0 = v.x; v1 = v.y; v2 = v.z; v3 = v.w;
    }
    float s = v0 + v1 + v2 + v3;
    float q = v0*v0 + v1*v1 + v2*v2 + v3*v3;
    #pragma unroll
    for (int off = 32; off >= 1; off >>= 1) {
        s += __shfl_down(s, off);
        q += __shfl_down(q, off);
    }
    __shared__ float ss[4], qq[4];
    if ((t & 63) == 0) { ss[t >> 6] = s; qq[t >> 6] = q; }
    __syncthreads();
    s = ss[0] + ss[1] + ss[2] + ss[3];
    q = qq[0] + qq[1] + qq[2] + qq[3];
    float mu = s * (1.f/DV);
    float var = q * (1.f/DV) - mu*mu;
    float rs = rsqrtf(var + 1e-5f);
    int d = t * 4;
    u16x4 o;
    o[0] = f2bf((v0 - mu)*rs*w[d+0] + b[d+0]);
    o[1] = f2bf((v1 - mu)*rs*w[d+1] + b[d+1]);
    o[2] = f2bf((v2 - mu)*rs*w[d+2] + b[d+2]);
    o[3] = f2bf((v3 - mu)*rs*w[d+3] + b[d+3]);
    *(u16x4*)(out + (size_t)row*DV + d) = o;
}

// ---------------- time-shift mix: out = xn*c + shift(xn)*(1-c), 2 or 3 outputs ----------------
__global__ __launch_bounds__(256) void mix_kernel(
    const unsigned short* __restrict__ xn,
    const float* __restrict__ ck, const float* __restrict__ cv, const float* __restrict__ cr,
    unsigned short* __restrict__ ok, unsigned short* __restrict__ ov, unsigned short* __restrict__ orr)
{
    int gid = blockIdx.x * 256 + threadIdx.x;   // MM*DV/8 total
    int row = gid >> 7;
    int d0 = (gid & 127) << 3;
    size_t base = (size_t)row * DV + d0;
    u16x8 cur = *(const u16x8*)(xn + base);
    bool hp = (row & (TT - 1)) != 0;
    u16x8 prev = (u16x8)0;
    if (hp) prev = *(const u16x8*)(xn + base - DV);
    u16x8 rk, rv, rr2;
    #pragma unroll
    for (int e = 0; e < 8; ++e) {
        float xc = bf2f(cur[e]);
        float xp = hp ? bf2f(prev[e]) : 0.f;
        float a = ck[d0+e]; rk[e] = f2bf(xc*a + xp*(1.f-a));
        float bb = cv[d0+e]; rv[e] = f2bf(xc*bb + xp*(1.f-bb));
        if (orr) { float c = cr[d0+e]; rr2[e] = f2bf(xc*c + xp*(1.f-c)); }
    }
    *(u16x8*)(ok + base) = rk;
    *(u16x8*)(ov + base) = rv;
    if (orr) *(u16x8*)(orr + base) = rr2;
}

// ---------------- WKV chunk-parallel scan ----------------
__global__ __launch_bounds__(256) void wkv_phase1(
    const unsigned short* __restrict__ k, const unsigned short* __restrict__ v,
    const float* __restrict__ time_decay,
    float* __restrict__ saP, float* __restrict__ sbP, float* __restrict__ mP)
{
    int gid = blockIdx.x * 256 + threadIdx.x;      // 262144
    int d = gid & (DV - 1);
    int bc = gid >> 10;
    int b = bc >> 6, c = bc & (NCH - 1);
    float w = __expf(time_decay[d]);
    float alpha = 0.f, beta = 0.f, m = -1e30f;
    size_t base = ((size_t)b * TT + (size_t)c * LCH) * DV + d;
    for (int t = 0; t < LCH; ++t) {
        size_t idx = base + (size_t)t * DV;
        float kt = bf2f(k[idx]);
        float vt = bf2f(v[idx]);
        float wm = m - w;
        float tau = fmaxf(wm, kt);
        float d1 = __expf(wm - tau);
        float d2 = __expf(kt - tau);
        alpha = d1*alpha + d2*vt;
        beta  = d1*beta + d2;
        m = tau;
    }
    saP[gid] = alpha; sbP[gid] = beta; mP[gid] = m;
}

__global__ __launch_bounds__(256) void wkv_phase2(
    const float* __restrict__ time_decay,
    float* __restrict__ saP, float* __restrict__ sbP, float* __restrict__ mP)
{
    int gid = blockIdx.x * 256 + threadIdx.x;      // 4096
    int b = gid >> 10, d = gid & (DV - 1);
    float Lw = (float)LCH * __expf(time_decay[d]);
    float A = 0.f, Bv = 0.f, E = -1e30f;
    for (int c = 0; c < NCH; ++c) {
        int idx = ((b * NCH + c) << 10) + d;
        float sa = saP[idx], sb = sbP[idx], mc = mP[idx];
        saP[idx] = A; sbP[idx] = Bv; mP[idx] = E;
        float de = E - Lw;
        float m2 = fmaxf(de, mc);
        float e1 = __expf(de - m2);
        float e2 = __expf(mc - m2);
        A  = e1*A  + e2*sa;
        Bv = e1*Bv + e2*sb;
        E  = m2;
    }
}

__global__ __launch_bounds__(256) void wkv_phase3(
    const unsigned short* __restrict__ k, const unsigned short* __restrict__ v,
    const unsigned short* __restrict__ r,
    const float* __restrict__ time_decay, const float* __restrict__ time_first,
    const float* __restrict__ saP, const float* __restrict__ sbP, const float* __restrict__ mP,
    unsigned short* __restrict__ aout)
{
    int gid = blockIdx.x * 256 + threadIdx.x;      // 262144
    int d = gid & (DV - 1);
    int bc = gid >> 10;
    int b = bc >> 6, c = bc & (NCH - 1);
    float w = __expf(time_decay[d]);
    float u = time_first[d];
    float alpha = saP[gid], beta = sbP[gid], eps = mP[gid];
    size_t base = ((size_t)b * TT + (size_t)c * LCH) * DV + d;
    for (int t = 0; t < LCH; ++t) {
        size_t idx = base + (size_t)t * DV;
        float kt = bf2f(k[idx]);
        float vt = bf2f(v[idx]);
        float ukt = u + kt;
        float tau = fmaxf(ukt, eps);
        float e1 = __expf(eps - tau);
        float e2 = __expf(ukt - tau);
        float out = (e1*alpha + e2*vt) / (e1*beta + e2);
        float weps = eps - w;
        float tau2 = fmaxf(weps, kt);
        float d1 = __expf(weps - tau2);
        float d2 = __expf(kt - tau2);
        alpha = d1*alpha + d2*vt;
        beta  = d1*beta + d2;
        eps = tau2;
        float rt = bf2f(r[idx]);
        float sr = 1.f / (1.f + __expf(-rt));
        aout[idx] = f2bf(out * sr);
    }
}

// ---------------- bf16 MFMA GEMM: C = A[M,K] @ Bt[N,K]^T ----------------
// BK=64, global_load_lds(16B) staging into linear [128][64] LDS tiles with
// T2 XOR swizzle (rule #21: linear dest + inverse-swizzled SOURCE + swizzled READ).
// LDS slot (row, bcol16) holds logical col16 = bcol16 ^ (row & 7).
// MODE 1: C bf16 = acc
// MODE 2: C f32  = acc + res_f32
// MODE 3: C bf16 = relu(acc)^2
// MODE 4: C f32  = Cprev + sigmoid(gate_bf16) * acc
template<int MODE>
__global__ __launch_bounds__(256) void gemm_bf16(
    const short* __restrict__ A, const short* __restrict__ Bt,
    void* __restrict__ Cout, int M, int N, int K,
    const void* __restrict__ res, const unsigned short* __restrict__ gate)
{
    __shared__ short sA[128 * 64];
    __shared__ short sB[128 * 64];
    const int m0 = blockIdx.y * 128, n0 = blockIdx.x * 128;
    const int t = threadIdx.x;
    const int lane = t & 63, wv = t >> 6;
    const int wr = wv >> 1, wc = wv & 1;
    const int lm = lane & 15, lk = (lane >> 4) * 8;
    // staging: 16 chunks of 8 rows x 64 shorts (1024 B). wave wv stages chunks wv+4i.
    // lane l covers LDS bytes c*1024 + l*16 = (row = c*8 + l/8, bcol16 = l&7);
    // fetch global col16 = bcol16 ^ (row&7) so the linear write lands swizzled.
    const int srow = lane >> 3;                        // 0..7 within chunk
    const int sxcol = ((lane & 7) ^ srow) * 8;         // swizzled source col (shorts)
    f32x4 acc[4][4] = {};

    for (int k0 = 0; k0 < K; k0 += 64) {
        __syncthreads();   // previous iteration's ds_reads complete
        #pragma unroll
        for (int i = 0; i < 4; ++i) {
            int c = wv + i * 4;
            int row = c * 8 + srow;
            gl16(A  + (size_t)(m0 + row) * K + k0 + sxcol, sA + c * 512);
            gl16(Bt + (size_t)(n0 + row) * K + k0 + sxcol, sB + c * 512);
        }
        __syncthreads();   // drains vmcnt(0) before barrier
        #pragma unroll
        for (int kk = 0; kk < 2; ++kk) {
            const int c16 = kk * 4 + (lane >> 4);      // logical 16B col 0..7
            bf16x8 af[4], bfr[4];
            #pragma unroll
            for (int i = 0; i < 4; ++i) {
                int row = wr*64 + i*16 + lm;
                af[i] = *(const bf16x8*)&sA[row * 64 + ((c16 ^ (row & 7)) << 3)];
            }
            #pragma unroll
            for (int j = 0; j < 4; ++j) {
                int row = wc*64 + j*16 + lm;
                bfr[j] = *(const bf16x8*)&sB[row * 64 + ((c16 ^ (row & 7)) << 3)];
            }
            #pragma unroll
            for (int i = 0; i < 4; ++i)
                #pragma unroll
                for (int j = 0; j < 4; ++j)
                    acc[i][j] = __builtin_amdgcn_mfma_f32_16x16x32_bf16(af[i], bfr[j], acc[i][j], 0, 0, 0);
        }
    }

    #pragma unroll
    for (int i = 0; i < 4; ++i)
        #pragma unroll
        for (int j = 0; j < 4; ++j)
            #pragma unroll
            for (int rr = 0; rr < 4; ++rr) {
                int gm = m0 + wr*64 + i*16 + (lane >> 4)*4 + rr;
                int gn = n0 + wc*64 + j*16 + lm;
                size_t off = (size_t)gm * N + gn;
                float val = acc[i][j][rr];
                if (MODE == 1) {
                    ((unsigned short*)Cout)[off] = f2bf(val);
                } else if (MODE == 2) {
                    ((float*)Cout)[off] = val + ((const float*)res)[off];
                } else if (MODE == 3) {
                    float rl = fmaxf(val, 0.f);
                    ((unsigned short*)Cout)[off] = f2bf(rl * rl);
                } else {
                    float g = bf2f(gate[off]);
                    float sg = 1.f / (1.f + __expf(-g));
                    ((float*)Cout)[off] = ((float*)Cout)[off] + sg * val;
                }
            }
}

extern "C" void kernel_launch(void* const* d_in, const int* in_sizes, int n_in,
                              void* d_out, int out_size, void* d_ws, size_t ws_size,
                              hipStream_t stream) {
    const float* x          = (const float*)d_in[0];
    const float* ln1_w      = (const float*)d_in[1];
    const float* ln1_b      = (const float*)d_in[2];
    const float* ln2_w      = (const float*)d_in[3];
    const float* ln2_b      = (const float*)d_in[4];
    const float* time_decay = (const float*)d_in[5];
    const float* time_first = (const float*)d_in[6];
    const float* tmk        = (const float*)d_in[7];
    const float* tmv        = (const float*)d_in[8];
    const float* tmr        = (const float*)d_in[9];
    const float* w_key      = (const float*)d_in[10];
    const float* w_value    = (const float*)d_in[11];
    const float* w_recept   = (const float*)d_in[12];
    const float* w_output   = (const float*)d_in[13];
    const float* f_tmk      = (const float*)d_in[14];
    const float* f_tmr      = (const float*)d_in[15];
    const float* f_w_key    = (const float*)d_in[16];
    const float* f_w_recept = (const float*)d_in[17];
    const float* f_w_value  = (const float*)d_in[18];

    char* ws = (char*)d_ws;
    const size_t MB = 1ull << 20;
    if (ws_size < 160 * MB) {
        diag_kernel<<<1, 1, 0, stream>>>((float*)d_out, (float)ws_size);
        return;
    }

    // weights (bf16, transposed [N][K]) — 26 MiB total
    unsigned short* wkT  = (unsigned short*)(ws + 0*MB);    // [1024][1024]
    unsigned short* wvT  = (unsigned short*)(ws + 2*MB);
    unsigned short* wrT  = (unsigned short*)(ws + 4*MB);
    unsigned short* woT  = (unsigned short*)(ws + 6*MB);
    unsigned short* fwkT = (unsigned short*)(ws + 8*MB);    // [4096][1024]
    unsigned short* fwrT = (unsigned short*)(ws + 16*MB);   // [1024][1024]
    unsigned short* fwvT = (unsigned short*)(ws + 18*MB);   // [1024][4096]
    // WKV chunk summaries: 3 planes x 1 MiB
    float* saP = (float*)(ws + 26*MB);
    float* sbP = (float*)(ws + 27*MB);
    float* mP  = (float*)(ws + 28*MB);
    // four rotating 32-MiB activation slots ([16384][1024] bf16 each)
    unsigned short* S0 = (unsigned short*)(ws + 32*MB);
    unsigned short* S1 = (unsigned short*)(ws + 64*MB);
    unsigned short* S2 = (unsigned short*)(ws + 96*MB);
    unsigned short* S3 = (unsigned short*)(ws + 128*MB);
    // attention liveness
    unsigned short* xn    = S0;
    unsigned short* xk    = S1;
    unsigned short* xv    = S2;
    unsigned short* xr    = S3;
    unsigned short* kbuf  = S0;  // xn dead
    unsigned short* vbuf  = S1;  // xk dead (k-GEMM already ran)
    unsigned short* rbuf  = S2;  // xv dead
    unsigned short* abuf  = S3;  // xr dead
    // x1 lives in d_out (f32), so ALL slots free for FF
    unsigned short* xn2   = S0;
    unsigned short* fkx   = S3;
    unsigned short* frx   = S2;
    unsigned short* frbuf = S0;  // xn2 dead
    unsigned short* hk    = S1;  // S1+S2 contiguous 64 MiB ([8192][4096] bf16); frx dead

    dim3 tb(32, 8);
    transpose_cast<<<dim3(32, 32),  tb, 0, stream>>>(w_key,      wkT,  1024, 1024);
    transpose_cast<<<dim3(32, 32),  tb, 0, stream>>>(w_value,    wvT,  1024, 1024);
    transpose_cast<<<dim3(32, 32),  tb, 0, stream>>>(w_recept,   wrT,  1024, 1024);
    transpose_cast<<<dim3(32, 32),  tb, 0, stream>>>(w_output,   woT,  1024, 1024);
    transpose_cast<<<dim3(128, 32), tb, 0, stream>>>(f_w_key,    fwkT, 1024, 4096);
    transpose_cast<<<dim3(32, 32),  tb, 0, stream>>>(f_w_recept, fwrT, 1024, 1024);
    transpose_cast<<<dim3(32, 128), tb, 0, stream>>>(f_w_value,  fwvT, 4096, 1024);

    // --- attention sub-block ---
    ln_kernel<false><<<MM, 256, 0, stream>>>(x, ln1_w, ln1_b, xn);
    mix_kernel<<<MM*DV/8/256, 256, 0, stream>>>(xn, tmk, tmv, tmr, xk, xv, xr);
    gemm_bf16<1><<<dim3(8, 128), 256, 0, stream>>>((const short*)xk, (const short*)wkT, kbuf, MM, 1024, 1024, nullptr, nullptr);
    gemm_bf16<1><<<dim3(8, 128), 256, 0, stream>>>((const short*)xv, (const short*)wvT, vbuf, MM, 1024, 1024, nullptr, nullptr);
    gemm_bf16<1><<<dim3(8, 128), 256, 0, stream>>>((const short*)xr, (const short*)wrT, rbuf, MM, 1024, 1024, nullptr, nullptr);
    wkv_phase1<<<BB*NCH*DV/256, 256, 0, stream>>>(kbuf, vbuf, time_decay, saP, sbP, mP);
    wkv_phase2<<<BB*DV/256, 256, 0, stream>>>(time_decay, saP, sbP, mP);
    wkv_phase3<<<BB*NCH*DV/256, 256, 0, stream>>>(kbuf, vbuf, rbuf, time_decay, time_first, saP, sbP, mP, abuf);
    // x1 = a @ w_output + x  -> f32 in d_out
    gemm_bf16<2><<<dim3(8, 128), 256, 0, stream>>>((const short*)abuf, (const short*)woT, (float*)d_out, MM, 1024, 1024, x, nullptr);

    // --- feed-forward sub-block ---
    ln_kernel<false><<<MM, 256, 0, stream>>>((float*)d_out, ln2_w, ln2_b, xn2);
    mix_kernel<<<MM*DV/8/256, 256, 0, stream>>>(xn2, f_tmk, f_tmr, nullptr, fkx, frx, nullptr);
    gemm_bf16<1><<<dim3(8, 128), 256, 0, stream>>>((const short*)frx, (const short*)fwrT, frbuf, MM, 1024, 1024, nullptr, nullptr);
    // two M-chunks of 8192 rows: hk = relu(fk)^2 (64 MiB), then d_out += sig(fr)*(hk@fwv)
    for (int m = 0; m < 2; ++m) {
        const size_t ro = (size_t)m * 8192;
        gemm_bf16<3><<<dim3(32, 64), 256, 0, stream>>>(
            (const short*)(fkx + ro * 1024), (const short*)fwkT, hk, 8192, 4096, 1024, nullptr, nullptr);
        gemm_bf16<4><<<dim3(8, 64), 256, 0, stream>>>(
            (const short*)hk, (const short*)fwvT, (float*)d_out + ro * 1024, 8192, 1024, 4096,
            nullptr, frbuf + ro * 1024);
    }
}